// Round 3
// baseline (311.043 us; speedup 1.0000x reference)
//
#include <hip/hip_runtime.h>

// SPDnet autoencoder, collapsed analytically:
//   out_b = D (E x_b E^T - EPS*I16) D^T + EPS*I128
// where E = Wenc2*Wenc1*Wenc0 (16x128), D = Wdec2*Wdec1*Wdec0 (128x16).
// Valid because: encoder ReEigs are no-ops (lambda_min >= 0.01 by Poincare
// interlacing with row-orthonormal W), LogEig->ExpEig->ReEig is identity, and
// decoder ReEigs clamp exactly the null space: reeig(W X W^T) =
// W X W^T + EPS*(I - W W^T) when eig(X) >= EPS and W has orthonormal columns.

#define SPD_EPS 1e-4f

typedef float nfloat4 __attribute__((ext_vector_type(4)));  // native vec for nt-store

// ---------------- setup: build E (16x128) and D (128x16) in workspace -------
__global__ __launch_bounds__(256) void setup_ED(
    const float* __restrict__ wenc0,  // 64x128
    const float* __restrict__ wenc1,  // 32x64
    const float* __restrict__ wenc2,  // 16x32
    const float* __restrict__ wdec0,  // 32x16
    const float* __restrict__ wdec1,  // 64x32
    const float* __restrict__ wdec2,  // 128x64
    float* __restrict__ wsE,          // out: 16x128
    float* __restrict__ wsD)          // out: 128x16
{
    __shared__ float e1[16 * 64];   // Wenc2 @ Wenc1
    __shared__ float d1[64 * 16];   // Wdec1 @ Wdec0
    const int t = threadIdx.x;

    // e1 = Wenc2(16x32) @ Wenc1(32x64)
#pragma unroll
    for (int r = 0; r < 4; ++r) {
        int o = t + 256 * r;
        int i = o >> 6, j = o & 63;
        float acc = 0.f;
#pragma unroll
        for (int k = 0; k < 32; ++k) acc += wenc2[i * 32 + k] * wenc1[k * 64 + j];
        e1[o] = acc;
    }
    // d1 = Wdec1(64x32) @ Wdec0(32x16)
#pragma unroll
    for (int r = 0; r < 4; ++r) {
        int o = t + 256 * r;
        int p = o >> 4, m = o & 15;
        float acc = 0.f;
#pragma unroll
        for (int k = 0; k < 32; ++k) acc += wdec1[p * 32 + k] * wdec0[k * 16 + m];
        d1[o] = acc;
    }
    __syncthreads();
    // E = e1(16x64) @ Wenc0(64x128)
#pragma unroll
    for (int r = 0; r < 8; ++r) {
        int o = t + 256 * r;
        int i = o >> 7, j = o & 127;
        float acc = 0.f;
#pragma unroll
        for (int k = 0; k < 64; ++k) acc += e1[i * 64 + k] * wenc0[k * 128 + j];
        wsE[o] = acc;
    }
    // D = Wdec2(128x64) @ d1(64x16)
#pragma unroll
    for (int r = 0; r < 8; ++r) {
        int o = t + 256 * r;
        int p = o >> 4, m = o & 15;
        float acc = 0.f;
#pragma unroll
        for (int k = 0; k < 64; ++k) acc += wdec2[p * 64 + k] * d1[k * 16 + m];
        wsD[o] = acc;
    }
}

// ---------------- main: one block per batch element -------------------------
// Thread mapping (all stages): jq = t&31 owns column quad [4jq,4jq+4);
// g = t>>5 owns rows {2g, 2g+1} of the 16-row intermediates.
// LDS (floats, stride 132 keeps float4 alignment: 528B % 16 == 0):
//   Esh  [0,2112)     E,   16x132
//   DT   [2112,4224)  D^T, 16x132  (DT[i][q] = D[q][i])
//   t1v  [4224,6336)  t1 = E@x, later reused for v = s@D^T
//   s    [6336,6592)  16x16
// Total 26368 B -> 6 blocks/CU by LDS. No x staging: stage 1 reads x directly
// with coalesced float4 loads (no barriers inside the k-loop).
__global__ __launch_bounds__(256) void spdnet_main(
    const float* __restrict__ x,    // B x 128 x 128
    const float* __restrict__ wsE,  // 16x128
    const float* __restrict__ wsD,  // 128x16
    float* __restrict__ out)        // B x 128 x 128
{
    __shared__ __align__(16) float smem[6592];
    float* Esh = smem;              // 16 x 132
    float* DT  = smem + 2112;       // 16 x 132
    float* t1v = smem + 4224;       // 16 x 132
    float* s   = smem + 6336;       // 256

    const int t  = threadIdx.x;
    const int jq = t & 31;
    const int g  = t >> 5;
    const int c4 = jq << 2;
    const size_t boff = (size_t)blockIdx.x * 16384;
    const float* __restrict__ xb = x + boff;
    float* __restrict__ ob = out + boff;

    // load E and D^T into LDS (8 elements per thread each)
#pragma unroll
    for (int r = 0; r < 8; ++r) {
        int o = t + 256 * r;                       // 0..2047
        Esh[(o >> 7) * 132 + (o & 127)] = wsE[o];  // wsE[i*128+k]
        DT[(o & 15) * 132 + (o >> 4)]   = wsD[o];  // wsD[p*16+m] -> DT[m][p]
    }
    __syncthreads();                                // barrier 1

    // ---- stage 1: t1 = E @ x_b, rows 2g/2g+1, cols c4..c4+3 ----
    float4 a0 = make_float4(0.f, 0.f, 0.f, 0.f);
    float4 a1 = make_float4(0.f, 0.f, 0.f, 0.f);
    const float* e0p = Esh + (2 * g) * 132;
    const float* e1p = e0p + 132;
#pragma unroll 8
    for (int k = 0; k < 128; ++k) {
        const float4 xv = *(const float4*)(xb + (k << 7) + c4);
        const float e0 = e0p[k];
        const float e1 = e1p[k];
        a0.x = fmaf(e0, xv.x, a0.x); a0.y = fmaf(e0, xv.y, a0.y);
        a0.z = fmaf(e0, xv.z, a0.z); a0.w = fmaf(e0, xv.w, a0.w);
        a1.x = fmaf(e1, xv.x, a1.x); a1.y = fmaf(e1, xv.y, a1.y);
        a1.z = fmaf(e1, xv.z, a1.z); a1.w = fmaf(e1, xv.w, a1.w);
    }
    *(float4*)(t1v + (2 * g) * 132 + c4)     = a0;
    *(float4*)(t1v + (2 * g + 1) * 132 + c4) = a1;
    __syncthreads();                                // barrier 2

    // ---- stage 2: s[i][m] = <t1 row i, E row m> - EPS*(i==m) ----
    {
        const int i = t >> 4, m = t & 15;
        const float4* tr = (const float4*)(t1v + i * 132);
        const float4* er = (const float4*)(Esh + m * 132);
        float acc = 0.f;
#pragma unroll
        for (int q = 0; q < 32; ++q) {
            const float4 a = tr[q], b = er[q];
            acc = fmaf(a.x, b.x, acc); acc = fmaf(a.y, b.y, acc);
            acc = fmaf(a.z, b.z, acc); acc = fmaf(a.w, b.w, acc);
        }
        if (i == m) acc -= SPD_EPS;
        s[t] = acc;                                 // s[i*16+m]
    }
    __syncthreads();                                // barrier 3 (t1 reads done)

    // ---- stage 3: v = s @ D^T (16x128), written over t1 ----
    {
        float4 b0 = make_float4(0.f, 0.f, 0.f, 0.f);
        float4 b1 = make_float4(0.f, 0.f, 0.f, 0.f);
        const float* s0p = s + (2 * g) * 16;
#pragma unroll
        for (int i = 0; i < 16; ++i) {
            const float4 d4 = *(const float4*)(DT + i * 132 + c4);
            const float s0 = s0p[i];
            const float s1 = s0p[16 + i];
            b0.x = fmaf(s0, d4.x, b0.x); b0.y = fmaf(s0, d4.y, b0.y);
            b0.z = fmaf(s0, d4.z, b0.z); b0.w = fmaf(s0, d4.w, b0.w);
            b1.x = fmaf(s1, d4.x, b1.x); b1.y = fmaf(s1, d4.y, b1.y);
            b1.z = fmaf(s1, d4.z, b1.z); b1.w = fmaf(s1, d4.w, b1.w);
        }
        *(float4*)(t1v + (2 * g) * 132 + c4)     = b0;
        *(float4*)(t1v + (2 * g + 1) * 132 + c4) = b1;
    }
    __syncthreads();                                // barrier 4

    // ---- stage 4: out[p][q] = sum_m D[p][m] v[m][q] + EPS*(p==q) ----
    {
        float4 vr[16];
#pragma unroll
        for (int m = 0; m < 16; ++m)
            vr[m] = *(const float4*)(t1v + m * 132 + c4);
#pragma unroll
        for (int r = 0; r < 16; ++r) {
            const int p = g + (r << 3);             // rows g, g+8, ..., g+120
            float4 o4 = make_float4(0.f, 0.f, 0.f, 0.f);
#pragma unroll
            for (int m = 0; m < 16; ++m) {
                const float dv = DT[m * 132 + p];   // broadcast read
                o4.x = fmaf(dv, vr[m].x, o4.x);
                o4.y = fmaf(dv, vr[m].y, o4.y);
                o4.z = fmaf(dv, vr[m].z, o4.z);
                o4.w = fmaf(dv, vr[m].w, o4.w);
            }
            const int d = p - c4;
            if (d >= 0 && d < 4) (&o4.x)[d] += SPD_EPS;
            nfloat4 nv = {o4.x, o4.y, o4.z, o4.w};
            __builtin_nontemporal_store(nv, (nfloat4*)(ob + (p << 7) + c4));
        }
    }
}

extern "C" void kernel_launch(void* const* d_in, const int* in_sizes, int n_in,
                              void* d_out, int out_size, void* d_ws, size_t ws_size,
                              hipStream_t stream) {
    const float* x     = (const float*)d_in[0];
    const float* wenc0 = (const float*)d_in[1];
    const float* wenc1 = (const float*)d_in[2];
    const float* wenc2 = (const float*)d_in[3];
    const float* wdec0 = (const float*)d_in[4];
    const float* wdec1 = (const float*)d_in[5];
    const float* wdec2 = (const float*)d_in[6];
    float* out = (float*)d_out;

    float* wsE = (float*)d_ws;          // 2048 floats
    float* wsD = wsE + 2048;            // 2048 floats

    const int B = in_sizes[0] / 16384;  // 2048

    setup_ED<<<1, 256, 0, stream>>>(wenc0, wenc1, wenc2, wdec0, wdec1, wdec2,
                                    wsE, wsD);
    spdnet_main<<<B, 256, 0, stream>>>(x, wsE, wsD, out);
}

// Round 4
// 290.091 us; speedup vs baseline: 1.0722x; 1.0722x over previous
//
#include <hip/hip_runtime.h>

// SPDnet autoencoder, collapsed analytically:
//   out_b = D (E x_b E^T - EPS*I16) D^T + EPS*I128
// where E = Wenc2*Wenc1*Wenc0 (16x128), D = Wdec2*Wdec1*Wdec0 (128x16).
// Valid because: encoder ReEigs are no-ops (lambda_min >= 0.01 by Poincare
// interlacing with row-orthonormal W), LogEig->ExpEig->ReEig is identity, and
// decoder ReEigs clamp exactly the null space: reeig(W X W^T) =
// W X W^T + EPS*(I - W W^T) when eig(X) >= EPS and W has orthonormal columns.

#define SPD_EPS 1e-4f

typedef float nfloat4 __attribute__((ext_vector_type(4)));  // native vec for nt ops

// ---------------- setup: build E (16x128) and D (128x16) in workspace -------
__global__ __launch_bounds__(256) void setup_ED(
    const float* __restrict__ wenc0,  // 64x128
    const float* __restrict__ wenc1,  // 32x64
    const float* __restrict__ wenc2,  // 16x32
    const float* __restrict__ wdec0,  // 32x16
    const float* __restrict__ wdec1,  // 64x32
    const float* __restrict__ wdec2,  // 128x64
    float* __restrict__ wsE,          // out: 16x128
    float* __restrict__ wsD)          // out: 128x16
{
    __shared__ float e1[16 * 64];   // Wenc2 @ Wenc1
    __shared__ float d1[64 * 16];   // Wdec1 @ Wdec0
    const int t = threadIdx.x;

#pragma unroll
    for (int r = 0; r < 4; ++r) {
        int o = t + 256 * r;
        int i = o >> 6, j = o & 63;
        float acc = 0.f;
#pragma unroll
        for (int k = 0; k < 32; ++k) acc += wenc2[i * 32 + k] * wenc1[k * 64 + j];
        e1[o] = acc;
    }
#pragma unroll
    for (int r = 0; r < 4; ++r) {
        int o = t + 256 * r;
        int p = o >> 4, m = o & 15;
        float acc = 0.f;
#pragma unroll
        for (int k = 0; k < 32; ++k) acc += wdec1[p * 32 + k] * wdec0[k * 16 + m];
        d1[o] = acc;
    }
    __syncthreads();
#pragma unroll
    for (int r = 0; r < 8; ++r) {
        int o = t + 256 * r;
        int i = o >> 7, j = o & 127;
        float acc = 0.f;
#pragma unroll
        for (int k = 0; k < 64; ++k) acc += e1[i * 64 + k] * wenc0[k * 128 + j];
        wsE[o] = acc;
    }
#pragma unroll
    for (int r = 0; r < 8; ++r) {
        int o = t + 256 * r;
        int p = o >> 4, m = o & 15;
        float acc = 0.f;
#pragma unroll
        for (int k = 0; k < 64; ++k) acc += wdec2[p * 64 + k] * d1[k * 16 + m];
        wsD[o] = acc;
    }
}

// ---------------- main: one block per batch element -------------------------
// Stage-1 mapping: kg=t&3 owns k in [32kg,32kg+32); ih=(t>>2)&1 owns t1 rows
// [8ih,8ih+8); q=t>>3 owns cols [4q,4q+4). Block reads x exactly once (unique
// loads; ih-pairs dedup in the coalescer), partial t1 in registers, k-sum
// completed by a 2-round __shfl_xor butterfly over kg (kg = lane&3).
// E2 is E in k-interleaved layout E2[((k&31)*4+(k>>5))*16 + i] so stage-1
// E-fragment reads are ds_read_b128 with <=2-way bank aliasing (free).
// Stages 2-4 use the old mapping (jq=t&31 col quad, g=t>>5).
// LDS (floats): Esh 16x132 | DT 16x132 | t1v 16x132 | s 256 | E2 2048
// = 34560 B -> 4 blocks/CU.
__global__ __launch_bounds__(256) void spdnet_main(
    const float* __restrict__ x,    // B x 128 x 128
    const float* __restrict__ wsE,  // 16x128
    const float* __restrict__ wsD,  // 128x16
    float* __restrict__ out)        // B x 128 x 128
{
    __shared__ __align__(16) float smem[8640];
    float* Esh = smem;              // 16 x 132 (row-major, stage 2)
    float* DT  = smem + 2112;       // 16 x 132 (D^T)
    float* t1v = smem + 4224;       // 16 x 132 (t1, then v)
    float* s   = smem + 6336;       // 16 x 16
    float* E2  = smem + 6592;       // 2048, k-interleaved E (stage 1)

    const int t = threadIdx.x;
    const size_t boff = (size_t)blockIdx.x * 16384;
    const float* __restrict__ xb = x + boff;
    float* __restrict__ ob = out + boff;

    // cooperative load: Esh, E2, DT
#pragma unroll
    for (int r = 0; r < 8; ++r) {
        int o = t + 256 * r;                        // 0..2047
        float ev = wsE[o];
        int i = o >> 7, k = o & 127;
        Esh[i * 132 + k] = ev;
        E2[((k & 31) * 4 + (k >> 5)) * 16 + i] = ev;
        DT[(o & 15) * 132 + (o >> 4)] = wsD[o];     // wsD[p*16+m] -> DT[m][p]
    }
    __syncthreads();                                 // barrier 1

    // ---- stage 1: t1 = E @ x_b, split-K over kg with register partials ----
    {
        const int kg = t & 3;
        const int ih = (t >> 2) & 1;
        const int q  = t >> 3;                       // 0..31
        const int sc4 = q << 2;
        const float* xq = xb + (kg << 5) * 128 + sc4;

        float ya[8][4];
#pragma unroll
        for (int i4 = 0; i4 < 8; ++i4)
#pragma unroll
            for (int c = 0; c < 4; ++c) ya[i4][c] = 0.f;

#pragma unroll
        for (int b = 0; b < 4; ++b) {
            nfloat4 xr[8];
#pragma unroll
            for (int j = 0; j < 8; ++j)
                xr[j] = __builtin_nontemporal_load(
                    (const nfloat4*)(xq + ((b << 3) + j) * 128));
#pragma unroll
            for (int j = 0; j < 8; ++j) {
                const int jj = (b << 3) + j;
                const float4 eL = *(const float4*)(E2 + ((jj << 2) + kg) * 16 + (ih << 3));
                const float4 eH = *(const float4*)(E2 + ((jj << 2) + kg) * 16 + (ih << 3) + 4);
                const float e[8] = {eL.x, eL.y, eL.z, eL.w, eH.x, eH.y, eH.z, eH.w};
                const float xv[4] = {xr[j][0], xr[j][1], xr[j][2], xr[j][3]};
#pragma unroll
                for (int i4 = 0; i4 < 8; ++i4)
#pragma unroll
                    for (int c = 0; c < 4; ++c)
                        ya[i4][c] = fmaf(e[i4], xv[c], ya[i4][c]);
            }
        }
        // butterfly k-sum over kg (= lane&3)
#pragma unroll
        for (int i4 = 0; i4 < 8; ++i4)
#pragma unroll
            for (int c = 0; c < 4; ++c) {
                float v = ya[i4][c];
                v += __shfl_xor(v, 1);
                v += __shfl_xor(v, 2);
                ya[i4][c] = v;
            }
        if (kg == 0) {
#pragma unroll
            for (int i4 = 0; i4 < 8; ++i4) {
                *(float4*)(t1v + ((ih << 3) + i4) * 132 + sc4) =
                    make_float4(ya[i4][0], ya[i4][1], ya[i4][2], ya[i4][3]);
            }
        }
    }
    __syncthreads();                                 // barrier 2

    // ---- stage 2: s[i][m] = <t1 row i, E row m> - EPS*(i==m) ----
    {
        const int i = t >> 4, m = t & 15;
        const float4* tr = (const float4*)(t1v + i * 132);
        const float4* er = (const float4*)(Esh + m * 132);
        float acc = 0.f;
#pragma unroll
        for (int qq = 0; qq < 32; ++qq) {
            const float4 a = tr[qq], bb = er[qq];
            acc = fmaf(a.x, bb.x, acc); acc = fmaf(a.y, bb.y, acc);
            acc = fmaf(a.z, bb.z, acc); acc = fmaf(a.w, bb.w, acc);
        }
        if (i == m) acc -= SPD_EPS;
        s[t] = acc;                                  // s[i*16+m]
    }
    __syncthreads();                                 // barrier 3

    // ---- stage 3: v = s @ D^T (16x128), written over t1 ----
    const int jq = t & 31;
    const int g  = t >> 5;
    const int c4 = jq << 2;
    {
        float4 b0 = make_float4(0.f, 0.f, 0.f, 0.f);
        float4 b1 = make_float4(0.f, 0.f, 0.f, 0.f);
        const float* s0p = s + (2 * g) * 16;
#pragma unroll
        for (int i = 0; i < 16; ++i) {
            const float4 d4 = *(const float4*)(DT + i * 132 + c4);
            const float s0 = s0p[i];
            const float s1 = s0p[16 + i];
            b0.x = fmaf(s0, d4.x, b0.x); b0.y = fmaf(s0, d4.y, b0.y);
            b0.z = fmaf(s0, d4.z, b0.z); b0.w = fmaf(s0, d4.w, b0.w);
            b1.x = fmaf(s1, d4.x, b1.x); b1.y = fmaf(s1, d4.y, b1.y);
            b1.z = fmaf(s1, d4.z, b1.z); b1.w = fmaf(s1, d4.w, b1.w);
        }
        __syncthreads();                             // barrier 4 (t1 reads done)
        *(float4*)(t1v + (2 * g) * 132 + c4)     = b0;
        *(float4*)(t1v + (2 * g + 1) * 132 + c4) = b1;
    }
    __syncthreads();                                 // barrier 5

    // ---- stage 4: out[p][q] = sum_m D[p][m] v[m][q] + EPS*(p==q) ----
    {
        float4 vr[16];
#pragma unroll
        for (int m = 0; m < 16; ++m)
            vr[m] = *(const float4*)(t1v + m * 132 + c4);
#pragma unroll
        for (int r = 0; r < 16; ++r) {
            const int p = g + (r << 3);              // rows g, g+8, ..., g+120
            float4 o4 = make_float4(0.f, 0.f, 0.f, 0.f);
#pragma unroll
            for (int m = 0; m < 16; ++m) {
                const float dv = DT[m * 132 + p];    // broadcast read
                o4.x = fmaf(dv, vr[m].x, o4.x);
                o4.y = fmaf(dv, vr[m].y, o4.y);
                o4.z = fmaf(dv, vr[m].z, o4.z);
                o4.w = fmaf(dv, vr[m].w, o4.w);
            }
            const int d = p - c4;
            if (d >= 0 && d < 4) (&o4.x)[d] += SPD_EPS;
            nfloat4 nv = {o4.x, o4.y, o4.z, o4.w};
            __builtin_nontemporal_store(nv, (nfloat4*)(ob + (p << 7) + c4));
        }
    }
}

extern "C" void kernel_launch(void* const* d_in, const int* in_sizes, int n_in,
                              void* d_out, int out_size, void* d_ws, size_t ws_size,
                              hipStream_t stream) {
    const float* x     = (const float*)d_in[0];
    const float* wenc0 = (const float*)d_in[1];
    const float* wenc1 = (const float*)d_in[2];
    const float* wenc2 = (const float*)d_in[3];
    const float* wdec0 = (const float*)d_in[4];
    const float* wdec1 = (const float*)d_in[5];
    const float* wdec2 = (const float*)d_in[6];
    float* out = (float*)d_out;

    float* wsE = (float*)d_ws;          // 2048 floats
    float* wsD = wsE + 2048;            // 2048 floats

    const int B = in_sizes[0] / 16384;  // 2048

    setup_ED<<<1, 256, 0, stream>>>(wenc0, wenc1, wenc2, wdec0, wdec1, wdec2,
                                    wsE, wsD);
    spdnet_main<<<B, 256, 0, stream>>>(x, wsE, wsD, out);
}